// Round 7
// baseline (76.987 us; speedup 1.0000x reference)
//
#include <hip/hip_runtime.h>
#include <hip/hip_bf16.h>
#include <math.h>

#define D 8192
#define NT 256

// ---------- wave (64-lane) shuffle reductions ----------
__device__ __forceinline__ float wave_sum(float v) {
    #pragma unroll
    for (int o = 32; o > 0; o >>= 1) v += __shfl_xor(v, o, 64);
    return v;
}

// ================= K1: per teacher row: top-8 + weights (also zeroes out[0]) ==========
__global__ __launch_bounds__(NT) void k_topk(
    const float* __restrict__ teacher, const float* __restrict__ center,
    const int* __restrict__ epoch_p,
    int* __restrict__ idx_ws, float* __restrict__ p_ws, float* __restrict__ out)
{
    const int row = blockIdx.x;     // 0..511
    const int t = threadIdx.x;
    const int lane = t & 63, w = t >> 6;
    __shared__ float svv[8][4];
    __shared__ int   sii[8][4];

    if (row == 0 && t == 0) out[0] = 0.f;   // loss accumulator reset (before k_main adds)

    const int e = epoch_p[0];
    const float temp = (e < 30) ? (0.04f + 0.03f * (float)e / 29.0f) : 0.07f;

    // z = teacher - center, 32 elems/thread
    float z[32];
    const float* trow = teacher + (size_t)row * D;
    #pragma unroll
    for (int i = 0; i < 8; ++i) {
        const int d = i * 1024 + t * 4;
        float4 tv = *(const float4*)(trow + d);
        float4 cv = *(const float4*)(center + d);
        z[i*4+0] = tv.x - cv.x; z[i*4+1] = tv.y - cv.y;
        z[i*4+2] = tv.z - cv.z; z[i*4+3] = tv.w - cv.w;
    }

    // cached thread-local argmax; only popped owner rescans
    float mvl = -INFINITY; int mil = 0;
    #pragma unroll
    for (int i = 0; i < 32; ++i)
        if (z[i] > mvl) { mvl = z[i]; mil = i; }

    float topv[8]; int topd[8];
    #pragma unroll 1
    for (int k = 0; k < 8; ++k) {
        float mv = mvl;
        int md = ((mil >> 2) << 10) + t * 4 + (mil & 3);
        #pragma unroll
        for (int o = 32; o > 0; o >>= 1) {
            float ov = __shfl_xor(mv, o, 64);
            int   od = __shfl_xor(md, o, 64);
            if (ov > mv) { mv = ov; md = od; }
        }
        if (lane == 0) { svv[k][w] = mv; sii[k][w] = md; }
        __syncthreads();
        float gv = svv[k][0]; int gd = sii[k][0];
        #pragma unroll
        for (int j = 1; j < 4; ++j)
            if (svv[k][j] > gv) { gv = svv[k][j]; gd = sii[k][j]; }
        topv[k] = gv; topd[k] = gd;
        if (((gd & 1023) >> 2) == t) {
            z[((gd >> 10) << 2) | (gd & 3)] = -INFINITY;
            mvl = -INFINITY; mil = 0;
            #pragma unroll
            for (int i = 0; i < 32; ++i)
                if (z[i] > mvl) { mvl = z[i]; mil = i; }
        }
    }

    if (t == 0) {
        float wgt[8]; float norm = 0.f;
        #pragma unroll
        for (int k = 0; k < 8; ++k) { wgt[k] = __expf((topv[k] - topv[0]) / temp); norm += wgt[k]; }
        const float invn = 1.0f / norm;
        #pragma unroll
        for (int k = 0; k < 8; ++k) {
            p_ws[row * 8 + k] = wgt[k] * invn;
            idx_ws[row * 8 + k] = topd[k];
        }
    }
}

// ========= K2: colsum (blocks 0..127, early overlap) + gather (blocks 128..2175) =====
__global__ __launch_bounds__(NT) void k_gather_colsum(
    const float* __restrict__ pred, const int* __restrict__ idx_ws,
    const float* __restrict__ p_ws, const float* __restrict__ teacher,
    float* __restrict__ g_ws, float* __restrict__ part_lse, float* __restrict__ part)
{
    const int bid = blockIdx.x;
    const int t = threadIdx.x;

    if (bid < 128) {
        // ---- colsum role: 16 row-chunks x 8 d-chunks ----
        const int rc = bid >> 3, dc = bid & 7;
        const int d0 = dc * 1024 + t * 4;
        const float* base = teacher + (size_t)rc * 32 * D + d0;
        float4 acc = make_float4(0.f, 0.f, 0.f, 0.f);
        #pragma unroll 4
        for (int r = 0; r < 32; ++r) {
            float4 x = *(const float4*)(base + (size_t)r * D);
            acc.x += x.x; acc.y += x.y; acc.z += x.z; acc.w += x.w;
        }
        *(float4*)(part + (size_t)rc * D + d0) = acc;
        return;
    }

    // ---- gather role ----
    const int gb  = bid - 128;         // 0..2047
    const int row = gb >> 2;           // 0..511
    const int ch  = gb & 3;            // 0..3
    const int lane = t & 63, w = t >> 6;
    const int d0 = ch * 2048 + t * 4;
    __shared__ float sred[4][8];

    int jk[8]; float pk[8];
    #pragma unroll
    for (int k = 0; k < 8; ++k) {
        jk[k] = idx_ws[row * 8 + k];
        pk[k] = p_ws[row * 8 + k];
    }

    float4 a0 = make_float4(0.f,0.f,0.f,0.f), a1 = make_float4(0.f,0.f,0.f,0.f);
    float se[8];
    #pragma unroll
    for (int k = 0; k < 8; ++k) {
        const float* prow = pred + (size_t)jk[k] * D;
        float4 x0 = *(const float4*)(prow + d0);
        float4 x1 = *(const float4*)(prow + d0 + 1024);
        // 10*P bounded (~|1.2|) -> plain sum-exp is exact logsumexp
        se[k] = __expf(x0.x*10.f) + __expf(x0.y*10.f) + __expf(x0.z*10.f) + __expf(x0.w*10.f)
              + __expf(x1.x*10.f) + __expf(x1.y*10.f) + __expf(x1.z*10.f) + __expf(x1.w*10.f);
        const float p = pk[k];
        a0.x += p*x0.x; a0.y += p*x0.y; a0.z += p*x0.z; a0.w += p*x0.w;
        a1.x += p*x1.x; a1.y += p*x1.y; a1.z += p*x1.z; a1.w += p*x1.w;
    }
    float* grow = g_ws + (size_t)row * D;
    *(float4*)(grow + d0)        = a0;
    *(float4*)(grow + d0 + 1024) = a1;

    #pragma unroll
    for (int k = 0; k < 8; ++k) se[k] = wave_sum(se[k]);
    if (lane == 0) {
        #pragma unroll
        for (int k = 0; k < 8; ++k) sred[w][k] = se[k];
    }
    __syncthreads();
    if (t < 8)
        part_lse[(size_t)gb * 8 + t] =
            sred[0][t] + sred[1][t] + sred[2][t] + sred[3][t];
}

// ==== K3: blocks 0,1 = c-term finalize->atomic loss; block 2 = center; 3.. = student ====
__global__ __launch_bounds__(NT) void k_main(
    const float* __restrict__ student, const float* __restrict__ g_ws,
    const float* __restrict__ p_ws, const float* __restrict__ part_lse,
    const float* __restrict__ part, const float* __restrict__ center,
    float* __restrict__ out)
{
    const int bid = blockIdx.x;
    const int t = threadIdx.x;
    const int lane = t & 63, w = t >> 6;

    if (bid < 2) {
        // ---- c-term finalize: r = bid*256 + t; pair multiplicity 7 (iq=0) or 6 (iq=1) ----
        __shared__ float sm4[4];
        const int r = (bid << 8) | t;
        float c = 0.f;
        #pragma unroll
        for (int k = 0; k < 8; ++k) {
            float s = part_lse[(size_t)(r*4+0)*8+k] + part_lse[(size_t)(r*4+1)*8+k]
                    + part_lse[(size_t)(r*4+2)*8+k] + part_lse[(size_t)(r*4+3)*8+k];
            c += p_ws[r * 8 + k] * __logf(s);
        }
        const float wgt = (bid == 0) ? 7.0f : 6.0f;
        float vv = wave_sum(c * wgt * (1.0f / 3328.0f));
        if (lane == 0) sm4[w] = vv;
        __syncthreads();
        if (t == 0) atomicAdd(out, sm4[0] + sm4[1] + sm4[2] + sm4[3]);
        return;
    }

    if (bid == 2) {
        // ---- center: batch_center, EMA, entropies ----
        __shared__ float sm4[4];
        float c[32], bc[32];
        #pragma unroll
        for (int i = 0; i < 8; ++i) {
            const int d = i * 1024 + t * 4;
            float4 cv = *(const float4*)(center + d);
            float4 s = make_float4(0.f, 0.f, 0.f, 0.f);
            for (int rc = 0; rc < 16; ++rc) {
                float4 p = *(const float4*)(part + (size_t)rc * D + d);
                s.x += p.x; s.y += p.y; s.z += p.z; s.w += p.w;
            }
            const float sc = 1.0f / 512.0f;
            bc[i*4+0] = s.x * sc; bc[i*4+1] = s.y * sc;
            bc[i*4+2] = s.z * sc; bc[i*4+3] = s.w * sc;
            c[i*4+0] = cv.x; c[i*4+1] = cv.y; c[i*4+2] = cv.z; c[i*4+3] = cv.w;
            out[3 + d + 0] = cv.x * 0.9f + bc[i*4+0] * 0.1f;
            out[3 + d + 1] = cv.y * 0.9f + bc[i*4+1] * 0.1f;
            out[3 + d + 2] = cv.z * 0.9f + bc[i*4+2] * 0.1f;
            out[3 + d + 3] = cv.w * 0.9f + bc[i*4+3] * 0.1f;
        }

        float mc = -INFINITY, mb = -INFINITY;
        #pragma unroll
        for (int i = 0; i < 32; ++i) { mc = fmaxf(mc, c[i]); mb = fmaxf(mb, bc[i]); }
        #pragma unroll
        for (int o = 32; o > 0; o >>= 1) {
            mc = fmaxf(mc, __shfl_xor(mc, o, 64));
            mb = fmaxf(mb, __shfl_xor(mb, o, 64));
        }
        if (lane == 0) sm4[w] = mc;
        __syncthreads();
        mc = fmaxf(fmaxf(sm4[0], sm4[1]), fmaxf(sm4[2], sm4[3]));
        __syncthreads();
        if (lane == 0) sm4[w] = mb;
        __syncthreads();
        mb = fmaxf(fmaxf(sm4[0], sm4[1]), fmaxf(sm4[2], sm4[3]));
        __syncthreads();

        float zc = 0.f, zb = 0.f;
        #pragma unroll
        for (int i = 0; i < 32; ++i) { zc += __expf(c[i] - mc); zb += __expf(bc[i] - mb); }
        zc = wave_sum(zc); zb = wave_sum(zb);
        if (lane == 0) sm4[w] = zc;
        __syncthreads();
        zc = sm4[0] + sm4[1] + sm4[2] + sm4[3];
        __syncthreads();
        if (lane == 0) sm4[w] = zb;
        __syncthreads();
        zb = sm4[0] + sm4[1] + sm4[2] + sm4[3];
        __syncthreads();
        const float lnZc = __logf(zc);

        float te = 0.f, en = 0.f;
        #pragma unroll
        for (int i = 0; i < 32; ++i) {
            const float lsm = c[i] - mc - lnZc;
            te += __expf(c[i] - mc) * lsm;
            en += __expf(bc[i] - mb) * lsm;
        }
        te = wave_sum(te); en = wave_sum(en);
        if (lane == 0) sm4[w] = te;
        __syncthreads();
        te = sm4[0] + sm4[1] + sm4[2] + sm4[3];
        __syncthreads();
        if (lane == 0) sm4[w] = en;
        __syncthreads();
        en = sm4[0] + sm4[1] + sm4[2] + sm4[3];
        if (t == 0) {
            out[1] = en / zb;
            out[2] = te / zc;
        }
        return;
    }

    // ---- student role: rows 256..2047; no max-subtraction (10*s bounded, exp fits f32) ----
    __shared__ float sred3[4][3];
    const int row = 253 + bid;          // bid 3..1794 -> rows 256..2047
    const int v = row >> 8;             // 1..7
    const int b = row & 255;

    float y[32];
    const float* srow = student + (size_t)row * D;
    #pragma unroll
    for (int i = 0; i < 8; ++i) {
        float4 x = *(const float4*)(srow + i * 1024 + t * 4);
        y[i*4+0] = __expf(x.x * 10.f); y[i*4+1] = __expf(x.y * 10.f);
        y[i*4+2] = __expf(x.z * 10.f); y[i*4+3] = __expf(x.w * 10.f);
    }
    float zs = 0.f;
    #pragma unroll
    for (int i = 0; i < 32; ++i) zs += y[i];

    const float* g0 = g_ws + (size_t)b * D;
    const float* g1 = g_ws + (size_t)(256 + b) * D;
    float a0 = 0.f, a1 = 0.f;
    #pragma unroll
    for (int i = 0; i < 8; ++i) {
        float4 gg = *(const float4*)(g0 + i * 1024 + t * 4);
        a0 += y[i*4+0]*gg.x + y[i*4+1]*gg.y + y[i*4+2]*gg.z + y[i*4+3]*gg.w;
    }
    if (v >= 2) {
        #pragma unroll
        for (int i = 0; i < 8; ++i) {
            float4 gg = *(const float4*)(g1 + i * 1024 + t * 4);
            a1 += y[i*4+0]*gg.x + y[i*4+1]*gg.y + y[i*4+2]*gg.z + y[i*4+3]*gg.w;
        }
    }
    zs = wave_sum(zs); a0 = wave_sum(a0); a1 = wave_sum(a1);
    if (lane == 0) { sred3[w][0] = zs; sred3[w][1] = a0; sred3[w][2] = a1; }
    __syncthreads();
    if (t == 0) {
        const float Z  = sred3[0][0] + sred3[1][0] + sred3[2][0] + sred3[3][0];
        const float A0 = sred3[0][1] + sred3[1][1] + sred3[2][1] + sred3[3][1];
        const float A1 = sred3[0][2] + sred3[1][2] + sred3[2][2] + sred3[3][2];
        const float invZ = 1.0f / Z;
        float term = -10.f * A0 * invZ;
        if (v >= 2) term += -10.f * A1 * invZ;
        atomicAdd(out, term * (1.0f / 3328.0f));
    }
}

extern "C" void kernel_launch(void* const* d_in, const int* in_sizes, int n_in,
                              void* d_out, int out_size, void* d_ws, size_t ws_size,
                              hipStream_t stream) {
    const float* student = (const float*)d_in[0];
    const float* teacher = (const float*)d_in[1];
    const float* pred    = (const float*)d_in[2];
    const float* center  = (const float*)d_in[3];
    const int*   epoch   = (const int*)d_in[4];
    float* out = (float*)d_out;

    float* g_ws     = (float*)d_ws;                     // 512*8192 f (16 MB)
    float* part     = g_ws + (size_t)512 * D;           // 16*8192 f (512 KB)
    int*   idx_ws   = (int*)(part + (size_t)16 * D);    // 512*8 i
    float* p_ws     = (float*)(idx_ws + 512 * 8);       // 512*8 f
    float* part_lse = p_ws + 512 * 8;                   // 2048*8 f

    k_topk<<<512, NT, 0, stream>>>(teacher, center, epoch, idx_ws, p_ws, out);
    k_gather_colsum<<<2176, NT, 0, stream>>>(pred, idx_ws, p_ws, teacher,
                                             g_ws, part_lse, part);
    k_main<<<1795, NT, 0, stream>>>(student, g_ws, p_ws, part_lse, part, center, out);
}

// Round 8
// 71.464 us; speedup vs baseline: 1.0773x; 1.0773x over previous
//
#include <hip/hip_runtime.h>
#include <hip/hip_bf16.h>
#include <math.h>

#define D 8192
#define NT 256

// ---------- wave (64-lane) shuffle reductions ----------
__device__ __forceinline__ float wave_sum(float v) {
    #pragma unroll
    for (int o = 32; o > 0; o >>= 1) v += __shfl_xor(v, o, 64);
    return v;
}

// ================= K1: per teacher row: top-8 + weights (also zeroes out[0]) ==========
__global__ __launch_bounds__(NT) void k_topk(
    const float* __restrict__ teacher, const float* __restrict__ center,
    const int* __restrict__ epoch_p,
    int* __restrict__ idx_ws, float* __restrict__ p_ws, float* __restrict__ out)
{
    const int row = blockIdx.x;     // 0..511
    const int t = threadIdx.x;
    const int lane = t & 63, w = t >> 6;
    __shared__ float svv[8][4];
    __shared__ int   sii[8][4];

    if (row == 0 && t == 0) out[0] = 0.f;   // loss accumulator reset (before adds)

    const int e = epoch_p[0];
    const float temp = (e < 30) ? (0.04f + 0.03f * (float)e / 29.0f) : 0.07f;

    // z = teacher - center, 32 elems/thread
    float z[32];
    const float* trow = teacher + (size_t)row * D;
    #pragma unroll
    for (int i = 0; i < 8; ++i) {
        const int d = i * 1024 + t * 4;
        float4 tv = *(const float4*)(trow + d);
        float4 cv = *(const float4*)(center + d);
        z[i*4+0] = tv.x - cv.x; z[i*4+1] = tv.y - cv.y;
        z[i*4+2] = tv.z - cv.z; z[i*4+3] = tv.w - cv.w;
    }

    // cached thread-local argmax; only popped owner rescans
    float mvl = -INFINITY; int mil = 0;
    #pragma unroll
    for (int i = 0; i < 32; ++i)
        if (z[i] > mvl) { mvl = z[i]; mil = i; }

    float topv[8]; int topd[8];
    #pragma unroll 1
    for (int k = 0; k < 8; ++k) {
        float mv = mvl;
        int md = ((mil >> 2) << 10) + t * 4 + (mil & 3);
        #pragma unroll
        for (int o = 32; o > 0; o >>= 1) {
            float ov = __shfl_xor(mv, o, 64);
            int   od = __shfl_xor(md, o, 64);
            if (ov > mv) { mv = ov; md = od; }
        }
        if (lane == 0) { svv[k][w] = mv; sii[k][w] = md; }
        __syncthreads();
        float gv = svv[k][0]; int gd = sii[k][0];
        #pragma unroll
        for (int j = 1; j < 4; ++j)
            if (svv[k][j] > gv) { gv = svv[k][j]; gd = sii[k][j]; }
        topv[k] = gv; topd[k] = gd;
        if (((gd & 1023) >> 2) == t) {
            z[((gd >> 10) << 2) | (gd & 3)] = -INFINITY;
            mvl = -INFINITY; mil = 0;
            #pragma unroll
            for (int i = 0; i < 32; ++i)
                if (z[i] > mvl) { mvl = z[i]; mil = i; }
        }
    }

    if (t == 0) {
        float wgt[8]; float norm = 0.f;
        #pragma unroll
        for (int k = 0; k < 8; ++k) { wgt[k] = __expf((topv[k] - topv[0]) / temp); norm += wgt[k]; }
        const float invn = 1.0f / norm;
        #pragma unroll
        for (int k = 0; k < 8; ++k) {
            p_ws[row * 8 + k] = wgt[k] * invn;
            idx_ws[row * 8 + k] = topd[k];
        }
    }
}

// ========= K2: gather predictor rows (blocks 0..2047) + teacher colsum (2048..2175) =====
__global__ __launch_bounds__(NT) void k_gather_colsum(
    const float* __restrict__ pred, const int* __restrict__ idx_ws,
    const float* __restrict__ p_ws, const float* __restrict__ teacher,
    float* __restrict__ g_ws, float* __restrict__ part_lse, float* __restrict__ part)
{
    const int bid = blockIdx.x;
    const int t = threadIdx.x;

    if (bid >= 2048) {
        // ---- colsum role ----
        const int cb = bid - 2048;
        const int rc = cb >> 3, dc = cb & 7;
        const int d0 = dc * 1024 + t * 4;
        const float* base = teacher + (size_t)rc * 32 * D + d0;
        float4 acc = make_float4(0.f, 0.f, 0.f, 0.f);
        #pragma unroll 4
        for (int r = 0; r < 32; ++r) {
            float4 x = *(const float4*)(base + (size_t)r * D);
            acc.x += x.x; acc.y += x.y; acc.z += x.z; acc.w += x.w;
        }
        *(float4*)(part + (size_t)rc * D + d0) = acc;
        return;
    }

    // ---- gather role ----
    const int row = bid >> 2;          // 0..511
    const int ch  = bid & 3;           // 0..3
    const int lane = t & 63, w = t >> 6;
    const int d0 = ch * 2048 + t * 4;
    __shared__ float sred[4][8];

    int jk[8]; float pk[8];
    #pragma unroll
    for (int k = 0; k < 8; ++k) {
        jk[k] = idx_ws[row * 8 + k];
        pk[k] = p_ws[row * 8 + k];
    }

    float4 a0 = make_float4(0.f,0.f,0.f,0.f), a1 = make_float4(0.f,0.f,0.f,0.f);
    float se[8];
    #pragma unroll
    for (int k = 0; k < 8; ++k) {
        const float* prow = pred + (size_t)jk[k] * D;
        float4 x0 = *(const float4*)(prow + d0);
        float4 x1 = *(const float4*)(prow + d0 + 1024);
        // 10*P bounded (~|1.2|) -> plain sum-exp is exact logsumexp
        se[k] = __expf(x0.x*10.f) + __expf(x0.y*10.f) + __expf(x0.z*10.f) + __expf(x0.w*10.f)
              + __expf(x1.x*10.f) + __expf(x1.y*10.f) + __expf(x1.z*10.f) + __expf(x1.w*10.f);
        const float p = pk[k];
        a0.x += p*x0.x; a0.y += p*x0.y; a0.z += p*x0.z; a0.w += p*x0.w;
        a1.x += p*x1.x; a1.y += p*x1.y; a1.z += p*x1.z; a1.w += p*x1.w;
    }
    float* grow = g_ws + (size_t)row * D;
    *(float4*)(grow + d0)        = a0;
    *(float4*)(grow + d0 + 1024) = a1;

    #pragma unroll
    for (int k = 0; k < 8; ++k) se[k] = wave_sum(se[k]);
    if (lane == 0) {
        #pragma unroll
        for (int k = 0; k < 8; ++k) sred[w][k] = se[k];
    }
    __syncthreads();
    if (t < 8)
        part_lse[(size_t)bid * 8 + t] =
            sred[0][t] + sred[1][t] + sred[2][t] + sred[3][t];
}

// ==== K3: bids 0,1 = c-term finalize; bid 2 = center; bids 3..1026 = student partials ====
// student-part block (b, ch): loads g0/g1 chunk ONCE, streams 7 student row-chunks,
// writes 21 partials {Z, A0, A1} x 7 to ps_ws. g_ws traffic: 16 MB total (was ~107 MB).
__global__ __launch_bounds__(NT) void k_main(
    const float* __restrict__ student, const float* __restrict__ g_ws,
    const float* __restrict__ p_ws, const float* __restrict__ part_lse,
    const float* __restrict__ part, const float* __restrict__ center,
    float* __restrict__ ps_ws, float* __restrict__ out)
{
    const int bid = blockIdx.x;
    const int t = threadIdx.x;
    const int lane = t & 63, w = t >> 6;

    if (bid < 2) {
        // ---- c-term finalize: r = bid*256 + t; pair multiplicity 7 (iq=0) or 6 (iq=1) ----
        __shared__ float sm4[4];
        const int r = (bid << 8) | t;
        float c = 0.f;
        #pragma unroll
        for (int k = 0; k < 8; ++k) {
            float s = part_lse[(size_t)(r*4+0)*8+k] + part_lse[(size_t)(r*4+1)*8+k]
                    + part_lse[(size_t)(r*4+2)*8+k] + part_lse[(size_t)(r*4+3)*8+k];
            c += p_ws[r * 8 + k] * __logf(s);
        }
        const float wgt = (bid == 0) ? 7.0f : 6.0f;
        float vv = wave_sum(c * wgt * (1.0f / 3328.0f));
        if (lane == 0) sm4[w] = vv;
        __syncthreads();
        if (t == 0) atomicAdd(out, sm4[0] + sm4[1] + sm4[2] + sm4[3]);
        return;
    }

    if (bid == 2) {
        // ---- center: batch_center, EMA, entropies ----
        __shared__ float sm4[4];
        float c[32], bc[32];
        #pragma unroll
        for (int i = 0; i < 8; ++i) {
            const int d = i * 1024 + t * 4;
            float4 cv = *(const float4*)(center + d);
            float4 s = make_float4(0.f, 0.f, 0.f, 0.f);
            for (int rc = 0; rc < 16; ++rc) {
                float4 p = *(const float4*)(part + (size_t)rc * D + d);
                s.x += p.x; s.y += p.y; s.z += p.z; s.w += p.w;
            }
            const float sc = 1.0f / 512.0f;
            bc[i*4+0] = s.x * sc; bc[i*4+1] = s.y * sc;
            bc[i*4+2] = s.z * sc; bc[i*4+3] = s.w * sc;
            c[i*4+0] = cv.x; c[i*4+1] = cv.y; c[i*4+2] = cv.z; c[i*4+3] = cv.w;
            out[3 + d + 0] = cv.x * 0.9f + bc[i*4+0] * 0.1f;
            out[3 + d + 1] = cv.y * 0.9f + bc[i*4+1] * 0.1f;
            out[3 + d + 2] = cv.z * 0.9f + bc[i*4+2] * 0.1f;
            out[3 + d + 3] = cv.w * 0.9f + bc[i*4+3] * 0.1f;
        }

        float mc = -INFINITY, mb = -INFINITY;
        #pragma unroll
        for (int i = 0; i < 32; ++i) { mc = fmaxf(mc, c[i]); mb = fmaxf(mb, bc[i]); }
        #pragma unroll
        for (int o = 32; o > 0; o >>= 1) {
            mc = fmaxf(mc, __shfl_xor(mc, o, 64));
            mb = fmaxf(mb, __shfl_xor(mb, o, 64));
        }
        if (lane == 0) sm4[w] = mc;
        __syncthreads();
        mc = fmaxf(fmaxf(sm4[0], sm4[1]), fmaxf(sm4[2], sm4[3]));
        __syncthreads();
        if (lane == 0) sm4[w] = mb;
        __syncthreads();
        mb = fmaxf(fmaxf(sm4[0], sm4[1]), fmaxf(sm4[2], sm4[3]));
        __syncthreads();

        float zc = 0.f, zb = 0.f;
        #pragma unroll
        for (int i = 0; i < 32; ++i) { zc += __expf(c[i] - mc); zb += __expf(bc[i] - mb); }
        zc = wave_sum(zc); zb = wave_sum(zb);
        if (lane == 0) sm4[w] = zc;
        __syncthreads();
        zc = sm4[0] + sm4[1] + sm4[2] + sm4[3];
        __syncthreads();
        if (lane == 0) sm4[w] = zb;
        __syncthreads();
        zb = sm4[0] + sm4[1] + sm4[2] + sm4[3];
        __syncthreads();
        const float lnZc = __logf(zc);

        float te = 0.f, en = 0.f;
        #pragma unroll
        for (int i = 0; i < 32; ++i) {
            const float lsm = c[i] - mc - lnZc;
            te += __expf(c[i] - mc) * lsm;
            en += __expf(bc[i] - mb) * lsm;
        }
        te = wave_sum(te); en = wave_sum(en);
        if (lane == 0) sm4[w] = te;
        __syncthreads();
        te = sm4[0] + sm4[1] + sm4[2] + sm4[3];
        __syncthreads();
        if (lane == 0) sm4[w] = en;
        __syncthreads();
        en = sm4[0] + sm4[1] + sm4[2] + sm4[3];
        if (t == 0) {
            out[1] = en / zb;
            out[2] = te / zc;
        }
        return;
    }

    // ---- student partials: sb = bid-3; b = sb>>2; ch = sb&3 ----
    __shared__ float sred21[4][21];
    const int sb = bid - 3;
    const int b = sb >> 2, ch = sb & 3;
    const int d0 = ch * 2048 + t * 4;

    // g chunks once into registers
    const float* g0p = g_ws + (size_t)b * D + d0;
    const float* g1p = g_ws + (size_t)(256 + b) * D + d0;
    const float4 g0a = *(const float4*)(g0p);
    const float4 g0b = *(const float4*)(g0p + 1024);
    const float4 g1a = *(const float4*)(g1p);
    const float4 g1b = *(const float4*)(g1p + 1024);

    float accZ[7], accA0[7], accA1[7];
    #pragma unroll
    for (int vi = 0; vi < 7; ++vi) { accZ[vi] = 0.f; accA0[vi] = 0.f; accA1[vi] = 0.f; }

    #pragma unroll
    for (int vi = 0; vi < 7; ++vi) {
        const int row = 256 * (vi + 1) + b;
        const float* sp = student + (size_t)row * D + d0;
        float4 x0 = *(const float4*)(sp);
        float4 x1 = *(const float4*)(sp + 1024);
        // no max-subtraction: 10*s bounded (~|50|), exp fits f32 (validated)
        float y0 = __expf(x0.x*10.f), y1 = __expf(x0.y*10.f);
        float y2 = __expf(x0.z*10.f), y3 = __expf(x0.w*10.f);
        float y4 = __expf(x1.x*10.f), y5 = __expf(x1.y*10.f);
        float y6 = __expf(x1.z*10.f), y7 = __expf(x1.w*10.f);
        accZ[vi]  = y0+y1+y2+y3+y4+y5+y6+y7;
        accA0[vi] = y0*g0a.x + y1*g0a.y + y2*g0a.z + y3*g0a.w
                  + y4*g0b.x + y5*g0b.y + y6*g0b.z + y7*g0b.w;
        accA1[vi] = y0*g1a.x + y1*g1a.y + y2*g1a.z + y3*g1a.w
                  + y4*g1b.x + y5*g1b.y + y6*g1b.z + y7*g1b.w;
    }

    #pragma unroll
    for (int vi = 0; vi < 7; ++vi) {
        accZ[vi]  = wave_sum(accZ[vi]);
        accA0[vi] = wave_sum(accA0[vi]);
        accA1[vi] = wave_sum(accA1[vi]);
    }
    if (lane == 0) {
        #pragma unroll
        for (int vi = 0; vi < 7; ++vi) {
            sred21[w][vi*3+0] = accZ[vi];
            sred21[w][vi*3+1] = accA0[vi];
            sred21[w][vi*3+2] = accA1[vi];
        }
    }
    __syncthreads();
    if (t < 21)
        ps_ws[(size_t)sb * 24 + t] =
            sred21[0][t] + sred21[1][t] + sred21[2][t] + sred21[3][t];
}

// ==== K4: student finalize: 7 blocks x 256 thr = 1792 rows; block-reduce -> 7 atomics ====
__global__ __launch_bounds__(NT) void k_sfinal(
    const float* __restrict__ ps_ws, float* __restrict__ out)
{
    const int t = threadIdx.x;
    const int lane = t & 63, w = t >> 6;
    __shared__ float sm4[4];
    const int g = blockIdx.x * NT + t;    // 0..1791
    const int vi = g >> 8;                // 0..6  (v = vi+1)
    const int b  = g & 255;

    float Z = 0.f, A0 = 0.f, A1 = 0.f;
    #pragma unroll
    for (int ch = 0; ch < 4; ++ch) {
        const float* p = ps_ws + (size_t)(b * 4 + ch) * 24 + vi * 3;
        Z += p[0]; A0 += p[1]; A1 += p[2];
    }
    float term = -10.f * (A0 + ((vi >= 1) ? A1 : 0.f)) / Z;
    float vv = wave_sum(term * (1.0f / 3328.0f));
    if (lane == 0) sm4[w] = vv;
    __syncthreads();
    if (t == 0) atomicAdd(out, sm4[0] + sm4[1] + sm4[2] + sm4[3]);
}

extern "C" void kernel_launch(void* const* d_in, const int* in_sizes, int n_in,
                              void* d_out, int out_size, void* d_ws, size_t ws_size,
                              hipStream_t stream) {
    const float* student = (const float*)d_in[0];
    const float* teacher = (const float*)d_in[1];
    const float* pred    = (const float*)d_in[2];
    const float* center  = (const float*)d_in[3];
    const int*   epoch   = (const int*)d_in[4];
    float* out = (float*)d_out;

    float* g_ws     = (float*)d_ws;                     // 512*8192 f (16 MB)
    float* part     = g_ws + (size_t)512 * D;           // 16*8192 f (512 KB)
    int*   idx_ws   = (int*)(part + (size_t)16 * D);    // 512*8 i
    float* p_ws     = (float*)(idx_ws + 512 * 8);       // 512*8 f
    float* part_lse = p_ws + 512 * 8;                   // 2048*8 f
    float* ps_ws    = part_lse + 2048 * 8;              // 1024*24 f

    k_topk<<<512, NT, 0, stream>>>(teacher, center, epoch, idx_ws, p_ws, out);
    k_gather_colsum<<<2176, NT, 0, stream>>>(pred, idx_ws, p_ws, teacher,
                                             g_ws, part_lse, part);
    k_main<<<1027, NT, 0, stream>>>(student, g_ws, p_ws, part_lse, part, center,
                                    ps_ws, out);
    k_sfinal<<<7, NT, 0, stream>>>(ps_ws, out);
}